// Round 1
// baseline (601.741 us; speedup 1.0000x reference)
//
#include <hip/hip_runtime.h>
#include <hip/hip_bf16.h>

constexpr int NUM = 1000000;
constexpr int DIM = 128;

// Mueller hash with torch/numpy int64 semantics: arithmetic shifts,
// wrapping 64-bit multiply (2nd mul exceeds 2^63 -> must wrap via uint64).
__device__ __forceinline__ int bloom_idx(long long t) {
    long long s = t;
    s = (long long)(((unsigned long long)((s >> 16) ^ s)) * 73244475ull);
    s = (long long)(((unsigned long long)((s >> 16) ^ s)) * 73244475ull);
    s = (s >> 16) ^ s;
    // jnp.mod semantics: result has sign of divisor (non-negative here)
    long long m = s % (long long)NUM;
    if (m < 0) m += NUM;
    return (int)m;
}

// One wave (64 lanes) per token. Each lane owns 2 output columns (float2).
// Lane computes the hash for probe k = lane&7; indices broadcast via shfl.
// Each row gather: 64 lanes x 8 B = 512 B contiguous -> one coalesced
// global_load_dwordx2 per row.
__global__ __launch_bounds__(256) void bloom_embed_kernel(
        const int* __restrict__ t,
        const float* __restrict__ W,
        float* __restrict__ out,
        int n_tokens) {
    const int gtid  = blockIdx.x * blockDim.x + threadIdx.x;
    const int token = gtid >> 6;           // wave id = token id
    const int lane  = threadIdx.x & 63;
    if (token >= n_tokens) return;

    const long long tv = (long long)t[token];
    const int my_idx = bloom_idx(tv + (long long)(lane & 7));

    float2 acc = make_float2(0.f, 0.f);
#pragma unroll
    for (int k = 0; k < 8; ++k) {
        const int idx = __shfl(my_idx, k);                 // wave-wide bcast
        const float2* row = (const float2*)(W + (size_t)idx * DIM);
        const float2 v = row[lane];                        // 512 B / row, coalesced
        acc.x += v.x;
        acc.y += v.y;
    }
    acc.x *= 0.125f;
    acc.y *= 0.125f;

    ((float2*)(out + (size_t)token * DIM))[lane] = acc;
}

extern "C" void kernel_launch(void* const* d_in, const int* in_sizes, int n_in,
                              void* d_out, int out_size, void* d_ws, size_t ws_size,
                              hipStream_t stream) {
    const int*   t = (const int*)d_in[0];     // 32*2048 = 65536 tokens
    const float* W = (const float*)d_in[1];   // [1e6, 128] fp32
    float*     out = (float*)d_out;           // [65536, 128] fp32

    const int n_tokens = in_sizes[0];         // 65536
    const int waves_per_block = 256 / 64;     // 4 tokens per block
    const int blocks = (n_tokens + waves_per_block - 1) / waves_per_block;

    bloom_embed_kernel<<<blocks, 256, 0, stream>>>(t, W, out, n_tokens);
}